// Round 9
// baseline (159.879 us; speedup 1.0000x reference)
//
#include <hip/hip_runtime.h>

// ---------------------------------------------------------------------------
// Fully-fused KAN-conv MLP: one block = one image through all layers.
// Cardinal cubic B-spline: basis_j(x) = B3(u - j), u = 2.5x+5.5 (4 taps).
// phi is SoA in LDS as F16: bas[pix] = uint4 (8 f16 taps, 1 ds_read_b128)
// + ext[pix] = silu fp32. Contraction via v_dot2_f32_f16 (packed f16 pairs,
// no unpack VALU). Heavy phases spread over ALL threads; tap-splits are
// wave-aligned (par = wave&1) so weight loads stay wave-uniform s_loads.
// conv1 windows -> f16 scratch; pool fused into h1-featurize. conv2/conv3
// partial sums combined inside the following featurize/repack pass.
// ---------------------------------------------------------------------------

typedef _Float16 h2 __attribute__((ext_vector_type(2)));

__device__ __forceinline__ h2 u2h(unsigned int u) {
  union { unsigned int x; h2 h; } v; v.x = u; return v.h;
}
__device__ __forceinline__ unsigned short f2h_bits(float x) {
  union { _Float16 h; unsigned short u; } v; v.h = (_Float16)x; return v.u;
}
__device__ __forceinline__ unsigned int pack2h(float a, float b) {
  return (unsigned int)f2h_bits(a) | ((unsigned int)f2h_bits(b) << 16);
}
__device__ __forceinline__ float fdot2(h2 a, h2 b, float c) {
  return __builtin_amdgcn_fdot2(a, b, c, false);
}

// Basis window (8 f16 packed in uint4) + silu, all in registers.
__device__ __forceinline__ void featurize_regs(float v, uint4& bs, float& silu) {
  silu = v / (1.0f + __expf(-v));
  bs.x = 0u; bs.y = 0u; bs.z = 0u; bs.w = 0u;
  float u = fmaf(v, 2.5f, 5.5f);
  if (u >= 0.0f && u < 11.0f) {
    float tf = floorf(u);
    float f = u - tf, f2 = f * f, f3 = f2 * f, om = 1.0f - f;
    const float c6 = 1.0f / 6.0f;
    float w0 = om * om * om * c6;
    float w1 = (3.0f * f3 - 6.0f * f2 + 4.0f) * c6;
    float w2 = (-3.0f * f3 + 3.0f * f2 + 3.0f * f + 1.0f) * c6;
    float w3 = f3 * c6;
    unsigned long long w01 =
        (unsigned long long)f2h_bits(w0) |
        ((unsigned long long)f2h_bits(w1) << 16) |
        ((unsigned long long)f2h_bits(w2) << 32) |
        ((unsigned long long)f2h_bits(w3) << 48);
    int t = (int)tf;                 // 0..10; window starts at slot t-3
    int s = 16 * t - 48;             // bit shift into 128-bit field
    unsigned long long lo, hi;
    if (s >= 0) {
      lo = (s < 64) ? (w01 << s) : 0ull;
      hi = (s == 0) ? 0ull : ((s < 64) ? (w01 >> (64 - s)) : (w01 << (s - 64)));
    } else {
      lo = w01 >> (-s);
      hi = 0ull;
    }
    bs.x = (unsigned int)lo; bs.y = (unsigned int)(lo >> 32);
    bs.z = (unsigned int)hi; bs.w = (unsigned int)(hi >> 32);
  }
}

// ---------------- prep: f16-paired conv weights + W1p ------------------------
__global__ __launch_bounds__(256) void k_prep(
    const float* __restrict__ bw1, const float* __restrict__ sw1,
    const float* __restrict__ bw2, const float* __restrict__ sw2,
    const float* __restrict__ bw3, const float* __restrict__ sw3,
    const float* __restrict__ w1,
    unsigned int* __restrict__ V1s, float* __restrict__ V1b,
    unsigned int* __restrict__ V2s, float* __restrict__ V2b,
    unsigned int* __restrict__ V3s, float* __restrict__ V3b,
    unsigned int* __restrict__ W1p) {
  int t = blockIdx.x * 256 + threadIdx.x;
  if (t < 180) {  // L1: 9 taps x 5 outs x 4 pairs
    int p = t & 3, o = (t >> 2) % 5, in = t / 20;
    V1s[t] = pack2h(sw1[(o * 9 + in) * 8 + 2 * p], sw1[(o * 9 + in) * 8 + 2 * p + 1]);
  }
  if (t < 45)  { int o = t % 5, in = t / 5; V1b[t] = bw1[o * 9 + in]; }
  if (t < 900) { // L2: 45 taps x 5 outs x 4 pairs
    int p = t & 3, o = (t >> 2) % 5, in = t / 20;
    V2s[t] = pack2h(sw2[(o * 45 + in) * 8 + 2 * p], sw2[(o * 45 + in) * 8 + 2 * p + 1]);
  }
  if (t < 225) { int o = t % 5, in = t / 5; V2b[t] = bw2[o * 45 + in]; }
  if (t < 360) { // L3: 45 taps x 2 outs x 4 pairs
    int p = t & 3, o = (t >> 2) & 1, in = t / 8;
    V3s[t] = pack2h(sw3[(o * 45 + in) * 8 + 2 * p], sw3[(o * 45 + in) * 8 + 2 * p + 1]);
  }
  if (t < 90)  { int o = t % 2, in = t / 2; V3b[t] = bw3[o * 45 + in]; }
  if (t < 81 * 512) {
    int kp = t >> 9, o = t & 511;
    W1p[t] = (o < 500) ? pack2h(w1[o * 162 + 2 * kp], w1[o * 162 + 2 * kp + 1]) : 0u;
  }
}

// ---------------- the fused per-image kernel --------------------------------
__global__ __launch_bounds__(256) void k_fused(
    const float* __restrict__ x,
    const unsigned int* __restrict__ V1s, const float* __restrict__ V1b,
    const unsigned int* __restrict__ V2s, const float* __restrict__ V2b,
    const unsigned int* __restrict__ V3s, const float* __restrict__ V3b,
    const unsigned int* __restrict__ W1p,
    const float* __restrict__ b1,
    const float* __restrict__ W2, const float* __restrict__ b2,
    float* __restrict__ out) {
  __shared__ uint4 bas[845];              // 13,520 B
  __shared__ float ext[845];              //  3,380 B (hpk aliases after conv3)
  __shared__ float hbuf[700];             //  2,800 B (fc1out + fc2 partials)
  __shared__ float scratch[1690];         //  6,760 B (co-f16 | conv partials)
  unsigned short* co  = (unsigned short*)scratch;
  unsigned int*  co32 = (unsigned int*)scratch;
  unsigned int*  hpk  = (unsigned int*)ext;   // 81 uints, live after P6
  const int b = blockIdx.x;
  const int tid = threadIdx.x;
  const int wv = tid >> 6, lane = tid & 63;

  // P1: featurize input image (784 px)
  for (int l = tid; l < 784; l += 256) {
    uint4 bs; float sl;
    featurize_regs(x[b * 784 + l], bs, sl);
    bas[l] = bs; ext[l] = sl;
  }
  __syncthreads();

  // P2: conv1 (1->5), ALL 676 windows over all threads -> co (f16)
  for (int l = tid; l < 676; l += 256) {
    int y = l / 26, xx = l % 26;
    float acc[5] = {0.f, 0.f, 0.f, 0.f, 0.f};
    #pragma unroll
    for (int ky = 0; ky < 3; ++ky) {
      #pragma unroll
      for (int kx = 0; kx < 3; ++kx) {
        int r = (y + ky) * 28 + xx + kx;
        uint4 q = bas[r];
        float sl = ext[r];
        h2 a0 = u2h(q.x), a1 = u2h(q.y), a2 = u2h(q.z), a3 = u2h(q.w);
        const unsigned int* wp = V1s + (ky * 3 + kx) * 20;
        const float* bp = V1b + (ky * 3 + kx) * 5;
        #pragma unroll
        for (int o = 0; o < 5; ++o) {
          float a = acc[o];
          a = fdot2(a0, u2h(wp[o * 4 + 0]), a);
          a = fdot2(a1, u2h(wp[o * 4 + 1]), a);
          a = fdot2(a2, u2h(wp[o * 4 + 2]), a);
          a = fdot2(a3, u2h(wp[o * 4 + 3]), a);
          acc[o] = fmaf(sl, bp[o], a);
        }
      }
    }
    #pragma unroll
    for (int o = 0; o < 5; ++o) co[o * 676 + l] = f2h_bits(acc[o]);
  }
  __syncthreads();

  // P3: 2x2 maxpool fused with h1-featurize (845 px)
  for (int l = tid; l < 845; l += 256) {
    int o = l / 169, p = l % 169;
    int py = p / 13, px = p % 13;
    int base = o * 338 + py * 26 + px;        // uint index (2 shorts per uint)
    h2 r0 = u2h(co32[base]);
    h2 r1 = u2h(co32[base + 13]);             // next row (+26 shorts)
    float m = fmaxf(fmaxf((float)r0.x, (float)r0.y),
                    fmaxf((float)r1.x, (float)r1.y));
    uint4 bs; float sl;
    featurize_regs(m, bs, sl);
    bas[l] = bs; ext[l] = sl;
  }
  __syncthreads();

  // P4: conv2 (5->5), parity-split over cky (wave-uniform) -> scratch partials
  {
    int par = wv & 1;
    int pos = (wv >> 1) * 64 + lane;          // waves 0/1: 0..63, 2/3: 64..127
    if (pos < 121) {
      int y = pos / 11, xx = pos % 11;
      float acc[5] = {0.f, 0.f, 0.f, 0.f, 0.f};
      #pragma unroll 1
      for (int cky = par; cky < 15; cky += 2) {
        int c = cky / 3, ky = cky % 3;
        int base = c * 169 + (y + ky) * 13 + xx;
        #pragma unroll
        for (int kx = 0; kx < 3; ++kx) {
          uint4 q = bas[base + kx];
          float sl = ext[base + kx];
          h2 a0 = u2h(q.x), a1 = u2h(q.y), a2 = u2h(q.z), a3 = u2h(q.w);
          const unsigned int* wp = V2s + (cky * 3 + kx) * 20;
          const float* bp = V2b + (cky * 3 + kx) * 5;
          #pragma unroll
          for (int o = 0; o < 5; ++o) {
            float a = acc[o];
            a = fdot2(a0, u2h(wp[o * 4 + 0]), a);
            a = fdot2(a1, u2h(wp[o * 4 + 1]), a);
            a = fdot2(a2, u2h(wp[o * 4 + 2]), a);
            a = fdot2(a3, u2h(wp[o * 4 + 3]), a);
            acc[o] = fmaf(sl, bp[o], a);
          }
        }
      }
      #pragma unroll
      for (int o = 0; o < 5; ++o)
        scratch[par * 605 + o * 121 + pos] = acc[o];
    }
  }
  __syncthreads();

  // P5: combine partials fused with h2-featurize (605 px)
  for (int l = tid; l < 605; l += 256) {
    float v = scratch[l] + scratch[605 + l];
    uint4 bs; float sl;
    featurize_regs(v, bs, sl);
    bas[l] = bs; ext[l] = sl;
  }
  __syncthreads();

  // P6: conv3 (5->2), parity-split over cky -> scratch partials
  {
    int par = wv & 1;
    int pos = (wv >> 1) * 64 + lane;
    if (pos < 81) {
      int y = pos / 9, xx = pos % 9;
      float acc[2] = {0.f, 0.f};
      #pragma unroll 1
      for (int cky = par; cky < 15; cky += 2) {
        int c = cky / 3, ky = cky % 3;
        int base = c * 121 + (y + ky) * 11 + xx;
        #pragma unroll
        for (int kx = 0; kx < 3; ++kx) {
          uint4 q = bas[base + kx];
          float sl = ext[base + kx];
          h2 a0 = u2h(q.x), a1 = u2h(q.y), a2 = u2h(q.z), a3 = u2h(q.w);
          const unsigned int* wp = V3s + (cky * 3 + kx) * 8;
          const float* bp = V3b + (cky * 3 + kx) * 2;
          #pragma unroll
          for (int o = 0; o < 2; ++o) {
            float a = acc[o];
            a = fdot2(a0, u2h(wp[o * 4 + 0]), a);
            a = fdot2(a1, u2h(wp[o * 4 + 1]), a);
            a = fdot2(a2, u2h(wp[o * 4 + 2]), a);
            a = fdot2(a3, u2h(wp[o * 4 + 3]), a);
            acc[o] = fmaf(sl, bp[o], a);
          }
        }
      }
      scratch[par * 162 + pos]      = acc[0];   // h3 layout o*81+pos
      scratch[par * 162 + 81 + pos] = acc[1];
    }
  }
  __syncthreads();

  // P6b: combine + repack h3 into f16 pairs hpk[81] (aliases dead ext)
  if (tid < 81) {
    float s0 = scratch[2 * tid]     + scratch[162 + 2 * tid];
    float s1 = scratch[2 * tid + 1] + scratch[162 + 2 * tid + 1];
    hpk[tid] = pack2h(s0, s1);
  }
  __syncthreads();

  // P7: fc1 (162->500) + bias + ReLU -> hbuf[200 + o]
  if (tid < 250) {
    float a0 = 0.0f, a1 = 0.0f;
    #pragma unroll 4
    for (int kp = 0; kp < 81; ++kp) {
      h2 hk = u2h(hpk[kp]);
      uint2 wvv = *(const uint2*)(W1p + kp * 512 + 2 * tid);
      a0 = fdot2(hk, u2h(wvv.x), a0);
      a1 = fdot2(hk, u2h(wvv.y), a1);
    }
    int o0 = 2 * tid, o1 = 2 * tid + 1;
    float v0 = a0 + b1[o0], v1 = a1 + b1[o1];
    hbuf[200 + o0] = v0 > 0.0f ? v0 : 0.0f;
    hbuf[200 + o1] = v1 > 0.0f ? v1 : 0.0f;
  }
  __syncthreads();

  // P8: fc2 partials: (o,part) -> hbuf[o*16+part]; k = part*4 + j*64
  if (tid < 160) {
    int o = tid >> 4, part = tid & 15;
    float s = 0.0f;
    #pragma unroll
    for (int j = 0; j < 8; ++j) {
      int k = part * 4 + j * 64;
      if (k <= 496) {
        float4 w = *(const float4*)&W2[o * 500 + k];
        float4 h = *(const float4*)&hbuf[200 + k];
        s += w.x * h.x + w.y * h.y + w.z * h.z + w.w * h.w;
      }
    }
    hbuf[tid] = s;
  }
  __syncthreads();

  // P9: reduce 16 partials per output, add bias, store
  if (tid < 10) {
    float s = 0.0f;
    #pragma unroll
    for (int p = 0; p < 16; ++p) s += hbuf[tid * 16 + p];
    out[b * 10 + tid] = s + b2[tid];
  }
}

// ---------------------------------------------------------------------------
extern "C" void kernel_launch(void* const* d_in, const int* in_sizes, int n_in,
                              void* d_out, int out_size, void* d_ws, size_t ws_size,
                              hipStream_t stream) {
  (void)in_sizes; (void)n_in; (void)out_size; (void)ws_size;
  const float* x   = (const float*)d_in[0];
  const float* bw1 = (const float*)d_in[1];
  const float* sw1 = (const float*)d_in[2];
  const float* bw2 = (const float*)d_in[3];
  const float* sw2 = (const float*)d_in[4];
  const float* bw3 = (const float*)d_in[5];
  const float* sw3 = (const float*)d_in[6];
  const float* w1  = (const float*)d_in[7];
  const float* b1  = (const float*)d_in[8];
  const float* w2  = (const float*)d_in[9];
  const float* b2  = (const float*)d_in[10];
  float* out = (float*)d_out;

  char* ws = (char*)d_ws;
  unsigned int* V1s = (unsigned int*)(ws);          // 180 u  (720 B)
  float*        V1b = (float*)(ws + 768);           // 45 f   (180 B)
  unsigned int* V2s = (unsigned int*)(ws + 1024);   // 900 u  (3,600 B)
  float*        V2b = (float*)(ws + 4672);          // 225 f  (900 B)
  unsigned int* V3s = (unsigned int*)(ws + 5632);   // 360 u  (1,440 B)
  float*        V3b = (float*)(ws + 7168);          // 90 f   (360 B)
  unsigned int* W1p = (unsigned int*)(ws + 7680);   // 81*512 u (165,888 B)

  k_prep<<<162, 256, 0, stream>>>(bw1, sw1, bw2, sw2, bw3, sw3, w1,
                                  V1s, V1b, V2s, V2b, V3s, V3b, W1p);
  k_fused<<<2048, 256, 0, stream>>>(x, V1s, V1b, V2s, V2b, V3s, V3b, W1p,
                                    b1, w2, b2, out);
}

// Round 10
// 141.722 us; speedup vs baseline: 1.1281x; 1.1281x over previous
//
#include <hip/hip_runtime.h>

// ---------------------------------------------------------------------------
// Fully-fused KAN-conv MLP: one block = one image through all layers.
// Cardinal cubic B-spline: basis_j(x) = B3(u - j), u = 2.5x+5.5 (4 taps).
// phi is SoA in LDS as F16: bas[pix] = uint4 (8 f16 taps, 1 ds_read_b128)
// + ext[pix] = silu fp32. Contraction via v_dot2_f32_f16 (packed f16 pairs).
// R9 lesson: do NOT trade extra LDS traffic for intra-block balance —
// co-resident blocks already hide idle lanes. This is R8's phase structure
// with ALL intermediates staged through dead regions of bas/ext so total
// LDS = 16.9 KB -> 8 blocks/CU (2048 blocks fully resident, no tail round).
// ---------------------------------------------------------------------------

typedef _Float16 h2 __attribute__((ext_vector_type(2)));

__device__ __forceinline__ h2 u2h(unsigned int u) {
  union { unsigned int x; h2 h; } v; v.x = u; return v.h;
}
__device__ __forceinline__ unsigned short f2h_bits(float x) {
  union { _Float16 h; unsigned short u; } v; v.h = (_Float16)x; return v.u;
}
__device__ __forceinline__ unsigned int pack2h(float a, float b) {
  return (unsigned int)f2h_bits(a) | ((unsigned int)f2h_bits(b) << 16);
}
__device__ __forceinline__ float fdot2(h2 a, h2 b, float c) {
  return __builtin_amdgcn_fdot2(a, b, c, false);
}

// Basis window (8 f16 packed in uint4) + silu, all in registers.
__device__ __forceinline__ void featurize_regs(float v, uint4& bs, float& silu) {
  silu = v / (1.0f + __expf(-v));
  bs.x = 0u; bs.y = 0u; bs.z = 0u; bs.w = 0u;
  float u = fmaf(v, 2.5f, 5.5f);
  if (u >= 0.0f && u < 11.0f) {
    float tf = floorf(u);
    float f = u - tf, f2 = f * f, f3 = f2 * f, om = 1.0f - f;
    const float c6 = 1.0f / 6.0f;
    float w0 = om * om * om * c6;
    float w1 = (3.0f * f3 - 6.0f * f2 + 4.0f) * c6;
    float w2 = (-3.0f * f3 + 3.0f * f2 + 3.0f * f + 1.0f) * c6;
    float w3 = f3 * c6;
    unsigned long long w01 =
        (unsigned long long)f2h_bits(w0) |
        ((unsigned long long)f2h_bits(w1) << 16) |
        ((unsigned long long)f2h_bits(w2) << 32) |
        ((unsigned long long)f2h_bits(w3) << 48);
    int t = (int)tf;                 // 0..10; window starts at slot t-3
    int s = 16 * t - 48;             // bit shift into 128-bit field
    unsigned long long lo, hi;
    if (s >= 0) {
      lo = (s < 64) ? (w01 << s) : 0ull;
      hi = (s == 0) ? 0ull : ((s < 64) ? (w01 >> (64 - s)) : (w01 << (s - 64)));
    } else {
      lo = w01 >> (-s);
      hi = 0ull;
    }
    bs.x = (unsigned int)lo; bs.y = (unsigned int)(lo >> 32);
    bs.z = (unsigned int)hi; bs.w = (unsigned int)(hi >> 32);
  }
}

// ---------------- prep: f16-paired conv weights + W1p ------------------------
__global__ __launch_bounds__(256) void k_prep(
    const float* __restrict__ bw1, const float* __restrict__ sw1,
    const float* __restrict__ bw2, const float* __restrict__ sw2,
    const float* __restrict__ bw3, const float* __restrict__ sw3,
    const float* __restrict__ w1,
    unsigned int* __restrict__ V1s, float* __restrict__ V1b,
    unsigned int* __restrict__ V2s, float* __restrict__ V2b,
    unsigned int* __restrict__ V3s, float* __restrict__ V3b,
    unsigned int* __restrict__ W1p) {
  int t = blockIdx.x * 256 + threadIdx.x;
  if (t < 180) {  // L1: 9 taps x 5 outs x 4 pairs
    int p = t & 3, o = (t >> 2) % 5, in = t / 20;
    V1s[t] = pack2h(sw1[(o * 9 + in) * 8 + 2 * p], sw1[(o * 9 + in) * 8 + 2 * p + 1]);
  }
  if (t < 45)  { int o = t % 5, in = t / 5; V1b[t] = bw1[o * 9 + in]; }
  if (t < 900) { // L2: 45 taps x 5 outs x 4 pairs
    int p = t & 3, o = (t >> 2) % 5, in = t / 20;
    V2s[t] = pack2h(sw2[(o * 45 + in) * 8 + 2 * p], sw2[(o * 45 + in) * 8 + 2 * p + 1]);
  }
  if (t < 225) { int o = t % 5, in = t / 5; V2b[t] = bw2[o * 45 + in]; }
  if (t < 360) { // L3: 45 taps x 2 outs x 4 pairs
    int p = t & 3, o = (t >> 2) & 1, in = t / 8;
    V3s[t] = pack2h(sw3[(o * 45 + in) * 8 + 2 * p], sw3[(o * 45 + in) * 8 + 2 * p + 1]);
  }
  if (t < 90)  { int o = t % 2, in = t / 2; V3b[t] = bw3[o * 45 + in]; }
  if (t < 81 * 512) {
    int kp = t >> 9, o = t & 511;
    W1p[t] = (o < 500) ? pack2h(w1[o * 162 + 2 * kp], w1[o * 162 + 2 * kp + 1]) : 0u;
  }
}

// ---------------- the fused per-image kernel --------------------------------
__global__ __launch_bounds__(256) void k_fused(
    const float* __restrict__ x,
    const unsigned int* __restrict__ V1s, const float* __restrict__ V1b,
    const unsigned int* __restrict__ V2s, const float* __restrict__ V2b,
    const unsigned int* __restrict__ V3s, const float* __restrict__ V3b,
    const unsigned int* __restrict__ W1p,
    const float* __restrict__ b1,
    const float* __restrict__ W2, const float* __restrict__ b2,
    float* __restrict__ out) {
  __shared__ uint4 bas[845];              // 13,520 B
  __shared__ float ext[845];              //  3,380 B
  // total 16,900 B -> 8 blocks/CU
  float*        basF = (float*)bas;       // dead after P6 -> fc1out+partials
  unsigned int* extU = (unsigned int*)ext;
  const int b = blockIdx.x;
  const int tid = threadIdx.x;

  // P1: featurize input image (784 px)
  for (int l = tid; l < 784; l += 256) {
    uint4 bs; float sl;
    featurize_regs(x[b * 784 + l], bs, sl);
    bas[l] = bs; ext[l] = sl;
  }
  __syncthreads();

  // P2: conv1 (1->5) + 2x2 maxpool (169 threads, 16 shared records each)
  float best[5];
  if (tid < 169) {
    int py = tid / 13, px = tid % 13;
    int r0 = py * 2, c0 = px * 2;
    float wacc[4][5];
    #pragma unroll
    for (int wi = 0; wi < 4; ++wi)
      #pragma unroll
      for (int o = 0; o < 5; ++o) wacc[wi][o] = 0.0f;
    #pragma unroll
    for (int r = 0; r < 4; ++r) {
      #pragma unroll
      for (int c = 0; c < 4; ++c) {
        uint4 q = bas[(r0 + r) * 28 + c0 + c];
        float sl = ext[(r0 + r) * 28 + c0 + c];
        h2 a0 = u2h(q.x), a1 = u2h(q.y), a2 = u2h(q.z), a3 = u2h(q.w);
        #pragma unroll
        for (int dy = 0; dy < 2; ++dy) {
          #pragma unroll
          for (int dx = 0; dx < 2; ++dx) {
            int ky = r - dy, kx = c - dx;
            if (ky >= 0 && ky < 3 && kx >= 0 && kx < 3) {
              const unsigned int* wp = V1s + (ky * 3 + kx) * 20;
              const float* bp = V1b + (ky * 3 + kx) * 5;
              #pragma unroll
              for (int o = 0; o < 5; ++o) {
                float acc = wacc[dy * 2 + dx][o];
                acc = fdot2(a0, u2h(wp[o * 4 + 0]), acc);
                acc = fdot2(a1, u2h(wp[o * 4 + 1]), acc);
                acc = fdot2(a2, u2h(wp[o * 4 + 2]), acc);
                acc = fdot2(a3, u2h(wp[o * 4 + 3]), acc);
                wacc[dy * 2 + dx][o] = fmaf(sl, bp[o], acc);
              }
            }
          }
        }
      }
    }
    #pragma unroll
    for (int o = 0; o < 5; ++o)
      best[o] = fmaxf(fmaxf(wacc[0][o], wacc[1][o]), fmaxf(wacc[2][o], wacc[3][o]));
  }
  __syncthreads();                        // all P2 reads of bas/ext done
  if (tid < 169) {
    #pragma unroll
    for (int o = 0; o < 5; ++o) ext[o * 169 + tid] = best[o];  // h1 -> ext
  }
  __syncthreads();

  // P3: featurize h1 (845 px): stage from ext, then overwrite bas/ext
  {
    float hv[4];
    #pragma unroll
    for (int i = 0; i < 4; ++i) {
      int l = tid + i * 256;
      hv[i] = (l < 845) ? ext[l] : 0.0f;
    }
    __syncthreads();
    #pragma unroll
    for (int i = 0; i < 4; ++i) {
      int l = tid + i * 256;
      if (l < 845) {
        uint4 bs; float sl;
        featurize_regs(hv[i], bs, sl);
        bas[l] = bs; ext[l] = sl;
      }
    }
  }
  __syncthreads();

  // P4: conv2 (5->5) on 121 threads
  float acc2[5];
  if (tid < 121) {
    int y = tid / 11, xx = tid % 11;
    #pragma unroll
    for (int o = 0; o < 5; ++o) acc2[o] = 0.0f;
    #pragma unroll 1
    for (int cky = 0; cky < 15; ++cky) {
      int c = cky / 3, ky = cky % 3;
      int base = c * 169 + (y + ky) * 13 + xx;
      #pragma unroll
      for (int kx = 0; kx < 3; ++kx) {
        uint4 q = bas[base + kx];
        float sl = ext[base + kx];
        h2 a0 = u2h(q.x), a1 = u2h(q.y), a2 = u2h(q.z), a3 = u2h(q.w);
        const unsigned int* wp = V2s + (cky * 3 + kx) * 20;
        const float* bp = V2b + (cky * 3 + kx) * 5;
        #pragma unroll
        for (int o = 0; o < 5; ++o) {
          float a = acc2[o];
          a = fdot2(a0, u2h(wp[o * 4 + 0]), a);
          a = fdot2(a1, u2h(wp[o * 4 + 1]), a);
          a = fdot2(a2, u2h(wp[o * 4 + 2]), a);
          a = fdot2(a3, u2h(wp[o * 4 + 3]), a);
          acc2[o] = fmaf(sl, bp[o], a);
        }
      }
    }
  }
  __syncthreads();
  if (tid < 121) {
    #pragma unroll
    for (int o = 0; o < 5; ++o) ext[o * 121 + tid] = acc2[o];  // h2 -> ext
  }
  __syncthreads();

  // P5: featurize h2 (605 px)
  {
    float hv[3];
    #pragma unroll
    for (int i = 0; i < 3; ++i) {
      int l = tid + i * 256;
      hv[i] = (l < 605) ? ext[l] : 0.0f;
    }
    __syncthreads();
    #pragma unroll
    for (int i = 0; i < 3; ++i) {
      int l = tid + i * 256;
      if (l < 605) {
        uint4 bs; float sl;
        featurize_regs(hv[i], bs, sl);
        bas[l] = bs; ext[l] = sl;
      }
    }
  }
  __syncthreads();

  // P6: conv3 (5->2) on 81 threads
  float acc3[2];
  if (tid < 81) {
    int y = tid / 9, xx = tid % 9;
    acc3[0] = 0.0f; acc3[1] = 0.0f;
    #pragma unroll 1
    for (int cky = 0; cky < 15; ++cky) {
      int c = cky / 3, ky = cky % 3;
      int base = c * 121 + (y + ky) * 11 + xx;
      #pragma unroll
      for (int kx = 0; kx < 3; ++kx) {
        uint4 q = bas[base + kx];
        float sl = ext[base + kx];
        h2 a0 = u2h(q.x), a1 = u2h(q.y), a2 = u2h(q.z), a3 = u2h(q.w);
        const unsigned int* wp = V3s + (cky * 3 + kx) * 8;
        const float* bp = V3b + (cky * 3 + kx) * 2;
        #pragma unroll
        for (int o = 0; o < 2; ++o) {
          float a = acc3[o];
          a = fdot2(a0, u2h(wp[o * 4 + 0]), a);
          a = fdot2(a1, u2h(wp[o * 4 + 1]), a);
          a = fdot2(a2, u2h(wp[o * 4 + 2]), a);
          a = fdot2(a3, u2h(wp[o * 4 + 3]), a);
          acc3[o] = fmaf(sl, bp[o], a);
        }
      }
    }
  }
  __syncthreads();
  if (tid < 81) { ext[tid] = acc3[0]; ext[81 + tid] = acc3[1]; }  // h3 -> ext[0..161]
  __syncthreads();

  // P6b: repack h3 into f16 pairs hpk = extU[256..336]
  if (tid < 81) extU[256 + tid] = pack2h(ext[2 * tid], ext[2 * tid + 1]);
  __syncthreads();

  // P7: fc1 (162->500) + bias + ReLU -> basF[160 + o]  (bas dead)
  if (tid < 250) {
    float a0 = 0.0f, a1 = 0.0f;
    #pragma unroll 4
    for (int kp = 0; kp < 81; ++kp) {
      h2 hk = u2h(extU[256 + kp]);
      uint2 wvv = *(const uint2*)(W1p + kp * 512 + 2 * tid);
      a0 = fdot2(hk, u2h(wvv.x), a0);
      a1 = fdot2(hk, u2h(wvv.y), a1);
    }
    int o0 = 2 * tid, o1 = 2 * tid + 1;
    float v0 = a0 + b1[o0], v1 = a1 + b1[o1];
    basF[160 + o0] = v0 > 0.0f ? v0 : 0.0f;
    basF[160 + o1] = v1 > 0.0f ? v1 : 0.0f;
  }
  __syncthreads();

  // P8: fc2 partials: (o,part) -> basF[o*16+part]; k = part*4 + j*64
  if (tid < 160) {
    int o = tid >> 4, part = tid & 15;
    float s = 0.0f;
    #pragma unroll
    for (int j = 0; j < 8; ++j) {
      int k = part * 4 + j * 64;
      if (k <= 496) {
        float4 w = *(const float4*)&W2[o * 500 + k];
        float4 h = *(const float4*)&basF[160 + k];
        s += w.x * h.x + w.y * h.y + w.z * h.z + w.w * h.w;
      }
    }
    basF[tid] = s;
  }
  __syncthreads();

  // P9: reduce 16 partials per output, add bias, store
  if (tid < 10) {
    float s = 0.0f;
    #pragma unroll
    for (int p = 0; p < 16; ++p) s += basF[tid * 16 + p];
    out[b * 10 + tid] = s + b2[tid];
  }
}

// ---------------------------------------------------------------------------
extern "C" void kernel_launch(void* const* d_in, const int* in_sizes, int n_in,
                              void* d_out, int out_size, void* d_ws, size_t ws_size,
                              hipStream_t stream) {
  (void)in_sizes; (void)n_in; (void)out_size; (void)ws_size;
  const float* x   = (const float*)d_in[0];
  const float* bw1 = (const float*)d_in[1];
  const float* sw1 = (const float*)d_in[2];
  const float* bw2 = (const float*)d_in[3];
  const float* sw2 = (const float*)d_in[4];
  const float* bw3 = (const float*)d_in[5];
  const float* sw3 = (const float*)d_in[6];
  const float* w1  = (const float*)d_in[7];
  const float* b1  = (const float*)d_in[8];
  const float* w2  = (const float*)d_in[9];
  const float* b2  = (const float*)d_in[10];
  float* out = (float*)d_out;

  char* ws = (char*)d_ws;
  unsigned int* V1s = (unsigned int*)(ws);          // 180 u  (720 B)
  float*        V1b = (float*)(ws + 768);           // 45 f   (180 B)
  unsigned int* V2s = (unsigned int*)(ws + 1024);   // 900 u  (3,600 B)
  float*        V2b = (float*)(ws + 4672);          // 225 f  (900 B)
  unsigned int* V3s = (unsigned int*)(ws + 5632);   // 360 u  (1,440 B)
  float*        V3b = (float*)(ws + 7168);          // 90 f   (360 B)
  unsigned int* W1p = (unsigned int*)(ws + 7680);   // 81*512 u (165,888 B)

  k_prep<<<162, 256, 0, stream>>>(bw1, sw1, bw2, sw2, bw3, sw3, w1,
                                  V1s, V1b, V2s, V2b, V3s, V3b, W1p);
  k_fused<<<2048, 256, 0, stream>>>(x, V1s, V1b, V2s, V2b, V3s, V3b, W1p,
                                    b1, w2, b2, out);
}

// Round 11
// 139.656 us; speedup vs baseline: 1.1448x; 1.0148x over previous
//
#include <hip/hip_runtime.h>

// ---------------------------------------------------------------------------
// Fully-fused KAN-conv MLP: one block = one image through all layers.
// Cardinal cubic B-spline: basis_j(x) = B3(u - j), u = 2.5x+5.5 (4 taps).
// phi is SoA in LDS as F16: bas[pix] = uint4 (8 f16 taps, 1 ds_read_b128)
// + ext[pix] = silu fp32. Contraction via v_dot2_f32_f16 (packed f16 pairs).
// LDS = 16.9 KB -> 8 blocks/CU. R11: conv inner loops batch ALL loads
// (weights s_load + record ds_read) per cky group up-front -> one lgkmcnt
// drain per ~90 VALU instead of ~6 (SMEM returns OOO, so any s_load use
// forces lgkmcnt(0) which also stalls ds_reads on the shared counter).
// ---------------------------------------------------------------------------

typedef _Float16 h2 __attribute__((ext_vector_type(2)));

__device__ __forceinline__ h2 u2h(unsigned int u) {
  union { unsigned int x; h2 h; } v; v.x = u; return v.h;
}
__device__ __forceinline__ unsigned short f2h_bits(float x) {
  union { _Float16 h; unsigned short u; } v; v.h = (_Float16)x; return v.u;
}
__device__ __forceinline__ unsigned int pack2h(float a, float b) {
  return (unsigned int)f2h_bits(a) | ((unsigned int)f2h_bits(b) << 16);
}
__device__ __forceinline__ float fdot2(h2 a, h2 b, float c) {
  return __builtin_amdgcn_fdot2(a, b, c, false);
}

// Basis window (8 f16 packed in uint4) + silu, all in registers.
__device__ __forceinline__ void featurize_regs(float v, uint4& bs, float& silu) {
  silu = v / (1.0f + __expf(-v));
  bs.x = 0u; bs.y = 0u; bs.z = 0u; bs.w = 0u;
  float u = fmaf(v, 2.5f, 5.5f);
  if (u >= 0.0f && u < 11.0f) {
    float tf = floorf(u);
    float f = u - tf, f2 = f * f, f3 = f2 * f, om = 1.0f - f;
    const float c6 = 1.0f / 6.0f;
    float w0 = om * om * om * c6;
    float w1 = (3.0f * f3 - 6.0f * f2 + 4.0f) * c6;
    float w2 = (-3.0f * f3 + 3.0f * f2 + 3.0f * f + 1.0f) * c6;
    float w3 = f3 * c6;
    unsigned long long w01 =
        (unsigned long long)f2h_bits(w0) |
        ((unsigned long long)f2h_bits(w1) << 16) |
        ((unsigned long long)f2h_bits(w2) << 32) |
        ((unsigned long long)f2h_bits(w3) << 48);
    int t = (int)tf;                 // 0..10; window starts at slot t-3
    int s = 16 * t - 48;             // bit shift into 128-bit field
    unsigned long long lo, hi;
    if (s >= 0) {
      lo = (s < 64) ? (w01 << s) : 0ull;
      hi = (s == 0) ? 0ull : ((s < 64) ? (w01 >> (64 - s)) : (w01 << (s - 64)));
    } else {
      lo = w01 >> (-s);
      hi = 0ull;
    }
    bs.x = (unsigned int)lo; bs.y = (unsigned int)(lo >> 32);
    bs.z = (unsigned int)hi; bs.w = (unsigned int)(hi >> 32);
  }
}

// ---------------- prep: f16-paired conv weights + W1p ------------------------
__global__ __launch_bounds__(256) void k_prep(
    const float* __restrict__ bw1, const float* __restrict__ sw1,
    const float* __restrict__ bw2, const float* __restrict__ sw2,
    const float* __restrict__ bw3, const float* __restrict__ sw3,
    const float* __restrict__ w1,
    unsigned int* __restrict__ V1s, float* __restrict__ V1b,
    unsigned int* __restrict__ V2s, float* __restrict__ V2b,
    unsigned int* __restrict__ V3s, float* __restrict__ V3b,
    unsigned int* __restrict__ W1p) {
  int t = blockIdx.x * 256 + threadIdx.x;
  if (t < 180) {  // L1: 9 taps x 5 outs x 4 pairs
    int p = t & 3, o = (t >> 2) % 5, in = t / 20;
    V1s[t] = pack2h(sw1[(o * 9 + in) * 8 + 2 * p], sw1[(o * 9 + in) * 8 + 2 * p + 1]);
  }
  if (t < 45)  { int o = t % 5, in = t / 5; V1b[t] = bw1[o * 9 + in]; }
  if (t < 900) { // L2: 45 taps x 5 outs x 4 pairs
    int p = t & 3, o = (t >> 2) % 5, in = t / 20;
    V2s[t] = pack2h(sw2[(o * 45 + in) * 8 + 2 * p], sw2[(o * 45 + in) * 8 + 2 * p + 1]);
  }
  if (t < 225) { int o = t % 5, in = t / 5; V2b[t] = bw2[o * 45 + in]; }
  if (t < 360) { // L3: 45 taps x 2 outs x 4 pairs
    int p = t & 3, o = (t >> 2) & 1, in = t / 8;
    V3s[t] = pack2h(sw3[(o * 45 + in) * 8 + 2 * p], sw3[(o * 45 + in) * 8 + 2 * p + 1]);
  }
  if (t < 90)  { int o = t % 2, in = t / 2; V3b[t] = bw3[o * 45 + in]; }
  if (t < 81 * 512) {
    int kp = t >> 9, o = t & 511;
    W1p[t] = (o < 500) ? pack2h(w1[o * 162 + 2 * kp], w1[o * 162 + 2 * kp + 1]) : 0u;
  }
}

// ---------------- the fused per-image kernel --------------------------------
__global__ __launch_bounds__(256) void k_fused(
    const float* __restrict__ x,
    const unsigned int* __restrict__ V1s, const float* __restrict__ V1b,
    const unsigned int* __restrict__ V2s, const float* __restrict__ V2b,
    const unsigned int* __restrict__ V3s, const float* __restrict__ V3b,
    const unsigned int* __restrict__ W1p,
    const float* __restrict__ b1,
    const float* __restrict__ W2, const float* __restrict__ b2,
    float* __restrict__ out) {
  __shared__ uint4 bas[845];              // 13,520 B
  __shared__ float ext[845];              //  3,380 B
  // total 16,900 B -> 8 blocks/CU
  float*        basF = (float*)bas;       // dead after P6 -> fc1out+partials
  unsigned int* extU = (unsigned int*)ext;
  const int b = blockIdx.x;
  const int tid = threadIdx.x;

  // P1: featurize input image (784 px)
  for (int l = tid; l < 784; l += 256) {
    uint4 bs; float sl;
    featurize_regs(x[b * 784 + l], bs, sl);
    bas[l] = bs; ext[l] = sl;
  }
  __syncthreads();

  // P2: conv1 (1->5) + 2x2 maxpool (169 threads); batch 4 records per row
  float best[5];
  if (tid < 169) {
    int py = tid / 13, px = tid % 13;
    int r0 = py * 2, c0 = px * 2;
    float wacc[4][5];
    #pragma unroll
    for (int wi = 0; wi < 4; ++wi)
      #pragma unroll
      for (int o = 0; o < 5; ++o) wacc[wi][o] = 0.0f;
    #pragma unroll
    for (int r = 0; r < 4; ++r) {
      uint4 q[4]; float sl[4];
      #pragma unroll
      for (int c = 0; c < 4; ++c) {
        q[c]  = bas[(r0 + r) * 28 + c0 + c];
        sl[c] = ext[(r0 + r) * 28 + c0 + c];
      }
      #pragma unroll
      for (int c = 0; c < 4; ++c) {
        h2 a0 = u2h(q[c].x), a1 = u2h(q[c].y), a2 = u2h(q[c].z), a3 = u2h(q[c].w);
        #pragma unroll
        for (int dy = 0; dy < 2; ++dy) {
          #pragma unroll
          for (int dx = 0; dx < 2; ++dx) {
            int ky = r - dy, kx = c - dx;
            if (ky >= 0 && ky < 3 && kx >= 0 && kx < 3) {
              const unsigned int* wp = V1s + (ky * 3 + kx) * 20;
              const float* bp = V1b + (ky * 3 + kx) * 5;
              #pragma unroll
              for (int o = 0; o < 5; ++o) {
                float acc = wacc[dy * 2 + dx][o];
                acc = fdot2(a0, u2h(wp[o * 4 + 0]), acc);
                acc = fdot2(a1, u2h(wp[o * 4 + 1]), acc);
                acc = fdot2(a2, u2h(wp[o * 4 + 2]), acc);
                acc = fdot2(a3, u2h(wp[o * 4 + 3]), acc);
                wacc[dy * 2 + dx][o] = fmaf(sl[c], bp[o], acc);
              }
            }
          }
        }
      }
    }
    #pragma unroll
    for (int o = 0; o < 5; ++o)
      best[o] = fmaxf(fmaxf(wacc[0][o], wacc[1][o]), fmaxf(wacc[2][o], wacc[3][o]));
  }
  __syncthreads();                        // all P2 reads of bas/ext done
  if (tid < 169) {
    #pragma unroll
    for (int o = 0; o < 5; ++o) ext[o * 169 + tid] = best[o];  // h1 -> ext
  }
  __syncthreads();

  // P3: featurize h1 (845 px): stage from ext, then overwrite bas/ext
  {
    float hv[4];
    #pragma unroll
    for (int i = 0; i < 4; ++i) {
      int l = tid + i * 256;
      hv[i] = (l < 845) ? ext[l] : 0.0f;
    }
    __syncthreads();
    #pragma unroll
    for (int i = 0; i < 4; ++i) {
      int l = tid + i * 256;
      if (l < 845) {
        uint4 bs; float sl;
        featurize_regs(hv[i], bs, sl);
        bas[l] = bs; ext[l] = sl;
      }
    }
  }
  __syncthreads();

  // P4: conv2 (5->5) on 121 threads; per-cky batched loads
  float acc2[5];
  if (tid < 121) {
    int y = tid / 11, xx = tid % 11;
    #pragma unroll
    for (int o = 0; o < 5; ++o) acc2[o] = 0.0f;
    #pragma unroll 1
    for (int cky = 0; cky < 15; ++cky) {
      int c = cky / 3, ky = cky % 3;
      int base = c * 169 + (y + ky) * 13 + xx;
      // batch: 6 DS reads (3 records)
      uint4 q0 = bas[base], q1 = bas[base + 1], q2 = bas[base + 2];
      float s0 = ext[base], s1 = ext[base + 1], s2 = ext[base + 2];
      // batch: 75 weight dwords (wave-uniform -> s_load bursts)
      uint4 wq[15]; float wb[15];
      const uint4* wp4 = (const uint4*)(V2s + cky * 60);
      const float* bp  = V2b + cky * 15;
      #pragma unroll
      for (int i = 0; i < 15; ++i) { wq[i] = wp4[i]; wb[i] = bp[i]; }
      // straight-line compute: 3 kx x 5 o
      #pragma unroll
      for (int kx = 0; kx < 3; ++kx) {
        uint4 q = (kx == 0) ? q0 : ((kx == 1) ? q1 : q2);
        float sl = (kx == 0) ? s0 : ((kx == 1) ? s1 : s2);
        h2 a0 = u2h(q.x), a1 = u2h(q.y), a2 = u2h(q.z), a3 = u2h(q.w);
        #pragma unroll
        for (int o = 0; o < 5; ++o) {
          uint4 w = wq[kx * 5 + o];
          float a = acc2[o];
          a = fdot2(a0, u2h(w.x), a);
          a = fdot2(a1, u2h(w.y), a);
          a = fdot2(a2, u2h(w.z), a);
          a = fdot2(a3, u2h(w.w), a);
          acc2[o] = fmaf(sl, wb[kx * 5 + o], a);
        }
      }
    }
  }
  __syncthreads();
  if (tid < 121) {
    #pragma unroll
    for (int o = 0; o < 5; ++o) ext[o * 121 + tid] = acc2[o];  // h2 -> ext
  }
  __syncthreads();

  // P5: featurize h2 (605 px)
  {
    float hv[3];
    #pragma unroll
    for (int i = 0; i < 3; ++i) {
      int l = tid + i * 256;
      hv[i] = (l < 605) ? ext[l] : 0.0f;
    }
    __syncthreads();
    #pragma unroll
    for (int i = 0; i < 3; ++i) {
      int l = tid + i * 256;
      if (l < 605) {
        uint4 bs; float sl;
        featurize_regs(hv[i], bs, sl);
        bas[l] = bs; ext[l] = sl;
      }
    }
  }
  __syncthreads();

  // P6: conv3 (5->2) on 81 threads; per-cky batched loads
  float acc3[2];
  if (tid < 81) {
    int y = tid / 9, xx = tid % 9;
    acc3[0] = 0.0f; acc3[1] = 0.0f;
    #pragma unroll 1
    for (int cky = 0; cky < 15; ++cky) {
      int c = cky / 3, ky = cky % 3;
      int base = c * 121 + (y + ky) * 11 + xx;
      uint4 q0 = bas[base], q1 = bas[base + 1], q2 = bas[base + 2];
      float s0 = ext[base], s1 = ext[base + 1], s2 = ext[base + 2];
      uint4 wq[6]; float wb[6];
      const uint4* wp4 = (const uint4*)(V3s + cky * 24);
      const float* bp  = V3b + cky * 6;
      #pragma unroll
      for (int i = 0; i < 6; ++i) { wq[i] = wp4[i]; wb[i] = bp[i]; }
      #pragma unroll
      for (int kx = 0; kx < 3; ++kx) {
        uint4 q = (kx == 0) ? q0 : ((kx == 1) ? q1 : q2);
        float sl = (kx == 0) ? s0 : ((kx == 1) ? s1 : s2);
        h2 a0 = u2h(q.x), a1 = u2h(q.y), a2 = u2h(q.z), a3 = u2h(q.w);
        #pragma unroll
        for (int o = 0; o < 2; ++o) {
          uint4 w = wq[kx * 2 + o];
          float a = acc3[o];
          a = fdot2(a0, u2h(w.x), a);
          a = fdot2(a1, u2h(w.y), a);
          a = fdot2(a2, u2h(w.z), a);
          a = fdot2(a3, u2h(w.w), a);
          acc3[o] = fmaf(sl, wb[kx * 2 + o], a);
        }
      }
    }
  }
  __syncthreads();
  if (tid < 81) { ext[tid] = acc3[0]; ext[81 + tid] = acc3[1]; }  // h3 -> ext[0..161]
  __syncthreads();

  // P6b: repack h3 into f16 pairs hpk = extU[256..336]
  if (tid < 81) extU[256 + tid] = pack2h(ext[2 * tid], ext[2 * tid + 1]);
  __syncthreads();

  // P7: fc1 (162->500) + bias + ReLU -> basF[160 + o]  (bas dead)
  if (tid < 250) {
    float a0 = 0.0f, a1 = 0.0f;
    #pragma unroll 4
    for (int kp = 0; kp < 81; ++kp) {
      h2 hk = u2h(extU[256 + kp]);
      uint2 wvv = *(const uint2*)(W1p + kp * 512 + 2 * tid);
      a0 = fdot2(hk, u2h(wvv.x), a0);
      a1 = fdot2(hk, u2h(wvv.y), a1);
    }
    int o0 = 2 * tid, o1 = 2 * tid + 1;
    float v0 = a0 + b1[o0], v1 = a1 + b1[o1];
    basF[160 + o0] = v0 > 0.0f ? v0 : 0.0f;
    basF[160 + o1] = v1 > 0.0f ? v1 : 0.0f;
  }
  __syncthreads();

  // P8: fc2 partials: (o,part) -> basF[o*16+part]; k = part*4 + j*64
  if (tid < 160) {
    int o = tid >> 4, part = tid & 15;
    float s = 0.0f;
    #pragma unroll
    for (int j = 0; j < 8; ++j) {
      int k = part * 4 + j * 64;
      if (k <= 496) {
        float4 w = *(const float4*)&W2[o * 500 + k];
        float4 h = *(const float4*)&basF[160 + k];
        s += w.x * h.x + w.y * h.y + w.z * h.z + w.w * h.w;
      }
    }
    basF[tid] = s;
  }
  __syncthreads();

  // P9: reduce 16 partials per output, add bias, store
  if (tid < 10) {
    float s = 0.0f;
    #pragma unroll
    for (int p = 0; p < 16; ++p) s += basF[tid * 16 + p];
    out[b * 10 + tid] = s + b2[tid];
  }
}

// ---------------------------------------------------------------------------
extern "C" void kernel_launch(void* const* d_in, const int* in_sizes, int n_in,
                              void* d_out, int out_size, void* d_ws, size_t ws_size,
                              hipStream_t stream) {
  (void)in_sizes; (void)n_in; (void)out_size; (void)ws_size;
  const float* x   = (const float*)d_in[0];
  const float* bw1 = (const float*)d_in[1];
  const float* sw1 = (const float*)d_in[2];
  const float* bw2 = (const float*)d_in[3];
  const float* sw2 = (const float*)d_in[4];
  const float* bw3 = (const float*)d_in[5];
  const float* sw3 = (const float*)d_in[6];
  const float* w1  = (const float*)d_in[7];
  const float* b1  = (const float*)d_in[8];
  const float* w2  = (const float*)d_in[9];
  const float* b2  = (const float*)d_in[10];
  float* out = (float*)d_out;

  char* ws = (char*)d_ws;
  unsigned int* V1s = (unsigned int*)(ws);          // 180 u  (720 B)
  float*        V1b = (float*)(ws + 768);           // 45 f   (180 B)
  unsigned int* V2s = (unsigned int*)(ws + 1024);   // 900 u  (3,600 B)
  float*        V2b = (float*)(ws + 4672);          // 225 f  (900 B)
  unsigned int* V3s = (unsigned int*)(ws + 5632);   // 360 u  (1,440 B)
  float*        V3b = (float*)(ws + 7168);          // 90 f   (360 B)
  unsigned int* W1p = (unsigned int*)(ws + 7680);   // 81*512 u (165,888 B)

  k_prep<<<162, 256, 0, stream>>>(bw1, sw1, bw2, sw2, bw3, sw3, w1,
                                  V1s, V1b, V2s, V2b, V3s, V3b, W1p);
  k_fused<<<2048, 256, 0, stream>>>(x, V1s, V1b, V2s, V2b, V3s, V3b, W1p,
                                    b1, w2, b2, out);
}

// Round 12
// 136.796 us; speedup vs baseline: 1.1687x; 1.0209x over previous
//
#include <hip/hip_runtime.h>

// ---------------------------------------------------------------------------
// Fully-fused KAN-conv MLP: ONE WAVE = ONE IMAGE, zero __syncthreads.
// Cardinal cubic B-spline: basis_j(x) = B3(u - j), u = 2.5x+5.5 (4 taps).
// Per-wave LDS slice: bas[pix] = uint4 (8 f16 taps) + slu[pix] = silu fp32.
// Wave lockstep + in-order per-wave DS pipe make cross-lane RAW safe without
// barriers; convs stage outputs in registers across their position-chunks,
// then featurize+write AFTER all reads (read-before-overwrite order).
// Contraction via v_dot2_f32_f16; conv weights wave-uniform -> s_loads.
// fc1: W1p4[kpq][o][4] uint4 (k-pairs), lanes consecutive in o (coalesced);
// fc2: W2 zero-padded to [10][512] in prep; wave shfl reduction.
// Blocks = 64 thr, 17.4 KB LDS -> 9/CU capacity, 2048 blocks fully resident.
// ---------------------------------------------------------------------------

typedef _Float16 h2 __attribute__((ext_vector_type(2)));

__device__ __forceinline__ h2 u2h(unsigned int u) {
  union { unsigned int x; h2 h; } v; v.x = u; return v.h;
}
__device__ __forceinline__ unsigned short f2h_bits(float x) {
  union { _Float16 h; unsigned short u; } v; v.h = (_Float16)x; return v.u;
}
__device__ __forceinline__ unsigned int pack2h(float a, float b) {
  return (unsigned int)f2h_bits(a) | ((unsigned int)f2h_bits(b) << 16);
}
__device__ __forceinline__ float fdot2(h2 a, h2 b, float c) {
  return __builtin_amdgcn_fdot2(a, b, c, false);
}

// Basis window (8 f16 packed in uint4) + silu, all in registers.
__device__ __forceinline__ void featurize_regs(float v, uint4& bs, float& silu) {
  silu = v / (1.0f + __expf(-v));
  bs.x = 0u; bs.y = 0u; bs.z = 0u; bs.w = 0u;
  float u = fmaf(v, 2.5f, 5.5f);
  if (u >= 0.0f && u < 11.0f) {
    float tf = floorf(u);
    float f = u - tf, f2 = f * f, f3 = f2 * f, om = 1.0f - f;
    const float c6 = 1.0f / 6.0f;
    float w0 = om * om * om * c6;
    float w1 = (3.0f * f3 - 6.0f * f2 + 4.0f) * c6;
    float w2 = (-3.0f * f3 + 3.0f * f2 + 3.0f * f + 1.0f) * c6;
    float w3 = f3 * c6;
    unsigned long long w01 =
        (unsigned long long)f2h_bits(w0) |
        ((unsigned long long)f2h_bits(w1) << 16) |
        ((unsigned long long)f2h_bits(w2) << 32) |
        ((unsigned long long)f2h_bits(w3) << 48);
    int t = (int)tf;                 // 0..10; window starts at slot t-3
    int s = 16 * t - 48;             // bit shift into 128-bit field
    unsigned long long lo, hi;
    if (s >= 0) {
      lo = (s < 64) ? (w01 << s) : 0ull;
      hi = (s == 0) ? 0ull : ((s < 64) ? (w01 >> (64 - s)) : (w01 << (s - 64)));
    } else {
      lo = w01 >> (-s);
      hi = 0ull;
    }
    bs.x = (unsigned int)lo; bs.y = (unsigned int)(lo >> 32);
    bs.z = (unsigned int)hi; bs.w = (unsigned int)(hi >> 32);
  }
}

// ---------------- prep: conv weights + W1p4 + padded W2 ---------------------
__global__ __launch_bounds__(256) void k_prep(
    const float* __restrict__ bw1, const float* __restrict__ sw1,
    const float* __restrict__ bw2, const float* __restrict__ sw2,
    const float* __restrict__ bw3, const float* __restrict__ sw3,
    const float* __restrict__ w1, const float* __restrict__ w2,
    unsigned int* __restrict__ V1s, float* __restrict__ V1b,
    unsigned int* __restrict__ V2s, float* __restrict__ V2b,
    unsigned int* __restrict__ V3s, float* __restrict__ V3b,
    unsigned int* __restrict__ W1p4, float* __restrict__ W2p) {
  int t = blockIdx.x * 256 + threadIdx.x;
  if (t < 180) {  // L1: 9 taps x 5 outs x 4 pairs
    int p = t & 3, o = (t >> 2) % 5, in = t / 20;
    V1s[t] = pack2h(sw1[(o * 9 + in) * 8 + 2 * p], sw1[(o * 9 + in) * 8 + 2 * p + 1]);
  }
  if (t < 45)  { int o = t % 5, in = t / 5; V1b[t] = bw1[o * 9 + in]; }
  if (t < 900) { // L2: 45 taps x 5 outs x 4 pairs
    int p = t & 3, o = (t >> 2) % 5, in = t / 20;
    V2s[t] = pack2h(sw2[(o * 45 + in) * 8 + 2 * p], sw2[(o * 45 + in) * 8 + 2 * p + 1]);
  }
  if (t < 225) { int o = t % 5, in = t / 5; V2b[t] = bw2[o * 45 + in]; }
  if (t < 360) { // L3: 45 taps x 2 outs x 4 pairs
    int p = t & 3, o = (t >> 2) & 1, in = t / 8;
    V3s[t] = pack2h(sw3[(o * 45 + in) * 8 + 2 * p], sw3[(o * 45 + in) * 8 + 2 * p + 1]);
  }
  if (t < 90)  { int o = t % 2, in = t / 2; V3b[t] = bw3[o * 45 + in]; }
  if (t < 43008) {  // W1p4[((kpq*512)+o)*4+j]: j-th k-pair of group kpq, out o
    int j = t & 3, o = (t >> 2) & 511, kpq = t >> 11;
    int kp = kpq * 4 + j;          // k-pair index, valid < 81
    W1p4[t] = (o < 500 && kp < 81)
                  ? pack2h(w1[o * 162 + 2 * kp], w1[o * 162 + 2 * kp + 1])
                  : 0u;
  }
  if (t < 5120) {   // W2p[10][512] zero-padded
    int o = t >> 9, k = t & 511;
    W2p[t] = (k < 500) ? w2[o * 500 + k] : 0.0f;
  }
}

// ---------------- the fused per-image kernel (one wave per block) -----------
__global__ __launch_bounds__(64, 2) void k_fused(
    const float* __restrict__ x,
    const unsigned int* __restrict__ V1s, const float* __restrict__ V1b,
    const unsigned int* __restrict__ V2s, const float* __restrict__ V2b,
    const unsigned int* __restrict__ V3s, const float* __restrict__ V3b,
    const unsigned int* __restrict__ W1p4, const float* __restrict__ W2p,
    const float* __restrict__ b1, const float* __restrict__ b2,
    float* __restrict__ out) {
  __shared__ uint4 bas[845];              // 13,520 B
  __shared__ float slu[845];              //  3,380 B
  float*        basF = (float*)bas;       // dead after conv3 -> fc1out[512]
  unsigned int* hpk  = (unsigned int*)slu + 256;  // 84 uints @byte 1024 (dead zone)
  const int b = blockIdx.x;
  const int lane = threadIdx.x;           // 0..63, one wave

  // P1: featurize input image (784 px)
  for (int l = lane; l < 784; l += 64) {
    uint4 bs; float sl;
    featurize_regs(x[b * 784 + l], bs, sl);
    bas[l] = bs; slu[l] = sl;
  }

  // P2: conv1 (1->5) + 2x2 maxpool; 169 outputs in 3 chunks, staged in regs
  float h1v[3][5];
  #pragma unroll 1
  for (int it = 0; it < 3; ++it) {
    int p = it * 64 + lane;
    if (p < 169) {
      int py = p / 13, px = p % 13;
      int r0 = py * 2, c0 = px * 2;
      float wacc[4][5];
      #pragma unroll
      for (int wi = 0; wi < 4; ++wi)
        #pragma unroll
        for (int o = 0; o < 5; ++o) wacc[wi][o] = 0.0f;
      #pragma unroll
      for (int r = 0; r < 4; ++r) {
        uint4 q[4]; float sl[4];
        #pragma unroll
        for (int c = 0; c < 4; ++c) {
          q[c]  = bas[(r0 + r) * 28 + c0 + c];
          sl[c] = slu[(r0 + r) * 28 + c0 + c];
        }
        #pragma unroll
        for (int c = 0; c < 4; ++c) {
          h2 a0 = u2h(q[c].x), a1 = u2h(q[c].y), a2 = u2h(q[c].z), a3 = u2h(q[c].w);
          #pragma unroll
          for (int dy = 0; dy < 2; ++dy) {
            #pragma unroll
            for (int dx = 0; dx < 2; ++dx) {
              int ky = r - dy, kx = c - dx;
              if (ky >= 0 && ky < 3 && kx >= 0 && kx < 3) {
                const unsigned int* wp = V1s + (ky * 3 + kx) * 20;
                const float* bp = V1b + (ky * 3 + kx) * 5;
                #pragma unroll
                for (int o = 0; o < 5; ++o) {
                  float acc = wacc[dy * 2 + dx][o];
                  acc = fdot2(a0, u2h(wp[o * 4 + 0]), acc);
                  acc = fdot2(a1, u2h(wp[o * 4 + 1]), acc);
                  acc = fdot2(a2, u2h(wp[o * 4 + 2]), acc);
                  acc = fdot2(a3, u2h(wp[o * 4 + 3]), acc);
                  wacc[dy * 2 + dx][o] = fmaf(sl[c], bp[o], acc);
                }
              }
            }
          }
        }
      }
      #pragma unroll
      for (int o = 0; o < 5; ++o)
        h1v[it][o] = fmaxf(fmaxf(wacc[0][o], wacc[1][o]),
                           fmaxf(wacc[2][o], wacc[3][o]));
    }
  }
  // write featurized h1 (after ALL conv1 reads; in-order DS keeps this safe)
  #pragma unroll 1
  for (int it = 0; it < 3; ++it) {
    int p = it * 64 + lane;
    if (p < 169) {
      #pragma unroll
      for (int o = 0; o < 5; ++o) {
        uint4 bs; float sl;
        featurize_regs(h1v[it][o], bs, sl);
        bas[o * 169 + p] = bs; slu[o * 169 + p] = sl;
      }
    }
  }

  // P4: conv2 (5->5); 121 outputs in 2 chunks, staged in regs
  float h2v[2][5];
  #pragma unroll 1
  for (int it = 0; it < 2; ++it) {
    int pos = it * 64 + lane;
    if (pos < 121) {
      int y = pos / 11, xx = pos % 11;
      float acc2[5];
      #pragma unroll
      for (int o = 0; o < 5; ++o) acc2[o] = 0.0f;
      #pragma unroll 1
      for (int cky = 0; cky < 15; ++cky) {
        int c = cky / 3, ky = cky % 3;
        int base = c * 169 + (y + ky) * 13 + xx;
        uint4 q0 = bas[base], q1 = bas[base + 1], q2 = bas[base + 2];
        float s0 = slu[base], s1 = slu[base + 1], s2 = slu[base + 2];
        uint4 wq[15]; float wb[15];
        const uint4* wp4 = (const uint4*)(V2s + cky * 60);
        const float* bp  = V2b + cky * 15;
        #pragma unroll
        for (int i = 0; i < 15; ++i) { wq[i] = wp4[i]; wb[i] = bp[i]; }
        #pragma unroll
        for (int kx = 0; kx < 3; ++kx) {
          uint4 q = (kx == 0) ? q0 : ((kx == 1) ? q1 : q2);
          float sl = (kx == 0) ? s0 : ((kx == 1) ? s1 : s2);
          h2 a0 = u2h(q.x), a1 = u2h(q.y), a2 = u2h(q.z), a3 = u2h(q.w);
          #pragma unroll
          for (int o = 0; o < 5; ++o) {
            uint4 w = wq[kx * 5 + o];
            float a = acc2[o];
            a = fdot2(a0, u2h(w.x), a);
            a = fdot2(a1, u2h(w.y), a);
            a = fdot2(a2, u2h(w.z), a);
            a = fdot2(a3, u2h(w.w), a);
            acc2[o] = fmaf(sl, wb[kx * 5 + o], a);
          }
        }
      }
      #pragma unroll
      for (int o = 0; o < 5; ++o) h2v[it][o] = acc2[o];
    }
  }
  // write featurized h2
  #pragma unroll 1
  for (int it = 0; it < 2; ++it) {
    int pos = it * 64 + lane;
    if (pos < 121) {
      #pragma unroll
      for (int o = 0; o < 5; ++o) {
        uint4 bs; float sl;
        featurize_regs(h2v[it][o], bs, sl);
        bas[o * 121 + pos] = bs; slu[o * 121 + pos] = sl;
      }
    }
  }

  // P6: conv3 (5->2); 81 outputs in 2 chunks, staged in regs
  float h3v[2][2];
  #pragma unroll 1
  for (int it = 0; it < 2; ++it) {
    int pos = it * 64 + lane;
    if (pos < 81) {
      int y = pos / 9, xx = pos % 9;
      float acc3[2] = {0.f, 0.f};
      #pragma unroll 1
      for (int cky = 0; cky < 15; ++cky) {
        int c = cky / 3, ky = cky % 3;
        int base = c * 121 + (y + ky) * 11 + xx;
        uint4 q0 = bas[base], q1 = bas[base + 1], q2 = bas[base + 2];
        float s0 = slu[base], s1 = slu[base + 1], s2 = slu[base + 2];
        uint4 wq[6]; float wb[6];
        const uint4* wp4 = (const uint4*)(V3s + cky * 24);
        const float* bp  = V3b + cky * 6;
        #pragma unroll
        for (int i = 0; i < 6; ++i) { wq[i] = wp4[i]; wb[i] = bp[i]; }
        #pragma unroll
        for (int kx = 0; kx < 3; ++kx) {
          uint4 q = (kx == 0) ? q0 : ((kx == 1) ? q1 : q2);
          float sl = (kx == 0) ? s0 : ((kx == 1) ? s1 : s2);
          h2 a0 = u2h(q.x), a1 = u2h(q.y), a2 = u2h(q.z), a3 = u2h(q.w);
          #pragma unroll
          for (int o = 0; o < 2; ++o) {
            uint4 w = wq[kx * 2 + o];
            float a = acc3[o];
            a = fdot2(a0, u2h(w.x), a);
            a = fdot2(a1, u2h(w.y), a);
            a = fdot2(a2, u2h(w.z), a);
            a = fdot2(a3, u2h(w.w), a);
            acc3[o] = fmaf(sl, wb[kx * 2 + o], a);
          }
        }
      }
      h3v[it][0] = acc3[0]; h3v[it][1] = acc3[1];
    }
  }
  // write h3 (f32) into slu[0..161] after all conv3 reads
  #pragma unroll 1
  for (int it = 0; it < 2; ++it) {
    int pos = it * 64 + lane;
    if (pos < 81) { slu[pos] = h3v[it][0]; slu[81 + pos] = h3v[it][1]; }
  }
  // pack h3 into f16 pairs hpk[84] (pad zeros)
  hpk[lane] = pack2h(slu[2 * lane], slu[2 * lane + 1]);
  {
    int i1 = 64 + lane;
    if (i1 < 84)
      hpk[i1] = (i1 < 81) ? pack2h(slu[2 * i1], slu[2 * i1 + 1]) : 0u;
  }

  // P7: fc1 (162->500) + bias + ReLU; 8 outs/lane (o = lane + 64i)
  float fa[8];
  #pragma unroll
  for (int i = 0; i < 8; ++i) fa[i] = 0.0f;
  {
    const uint4* hp4 = (const uint4*)hpk;
    #pragma unroll 1
    for (int kpq = 0; kpq < 21; ++kpq) {
      uint4 hk = hp4[kpq];                       // broadcast DS read
      const uint4* wrow = (const uint4*)W1p4 + kpq * 512 + lane;
      #pragma unroll
      for (int i = 0; i < 8; ++i) {
        uint4 wv = wrow[i * 64];                 // coalesced 16B/lane
        float a = fa[i];
        a = fdot2(u2h(hk.x), u2h(wv.x), a);
        a = fdot2(u2h(hk.y), u2h(wv.y), a);
        a = fdot2(u2h(hk.z), u2h(wv.z), a);
        a = fdot2(u2h(hk.w), u2h(wv.w), a);
        fa[i] = a;
      }
    }
  }
  #pragma unroll
  for (int i = 0; i < 8; ++i) {
    int o = lane + 64 * i;
    float bb = (o < 500) ? b1[o] : 0.0f;
    float v = fa[i] + bb;
    basF[o] = (v > 0.0f && o < 500) ? v : 0.0f;  // fc1out[512], zero-padded
  }

  // P8: fc2 (500->10): lane covers k = 8*lane..8*lane+7, shfl reduction
  float hv0, hv1, hv2, hv3, hv4, hv5, hv6, hv7;
  {
    const float4* hf = (const float4*)&basF[lane * 8];
    float4 ha = hf[0], hb = hf[1];
    hv0 = ha.x; hv1 = ha.y; hv2 = ha.z; hv3 = ha.w;
    hv4 = hb.x; hv5 = hb.y; hv6 = hb.z; hv7 = hb.w;
  }
  float acc10[10];
  #pragma unroll
  for (int o = 0; o < 10; ++o) {
    const float4* wp = (const float4*)&W2p[o * 512 + lane * 8];
    float4 w0 = wp[0], w1v = wp[1];
    float s = hv0 * w0.x + hv1 * w0.y + hv2 * w0.z + hv3 * w0.w;
    s += hv4 * w1v.x + hv5 * w1v.y + hv6 * w1v.z + hv7 * w1v.w;
    acc10[o] = s;
  }
  #pragma unroll
  for (int off = 32; off > 0; off >>= 1) {
    #pragma unroll
    for (int o = 0; o < 10; ++o) acc10[o] += __shfl_down(acc10[o], off);
  }
  if (lane == 0) {
    #pragma unroll
    for (int o = 0; o < 10; ++o) out[b * 10 + o] = acc10[o] + b2[o];
  }
}

// ---------------------------------------------------------------------------
extern "C" void kernel_launch(void* const* d_in, const int* in_sizes, int n_in,
                              void* d_out, int out_size, void* d_ws, size_t ws_size,
                              hipStream_t stream) {
  (void)in_sizes; (void)n_in; (void)out_size; (void)ws_size;
  const float* x   = (const float*)d_in[0];
  const float* bw1 = (const float*)d_in[1];
  const float* sw1 = (const float*)d_in[2];
  const float* bw2 = (const float*)d_in[3];
  const float* sw2 = (const float*)d_in[4];
  const float* bw3 = (const float*)d_in[5];
  const float* sw3 = (const float*)d_in[6];
  const float* w1  = (const float*)d_in[7];
  const float* b1  = (const float*)d_in[8];
  const float* w2  = (const float*)d_in[9];
  const float* b2  = (const float*)d_in[10];
  float* out = (float*)d_out;

  char* ws = (char*)d_ws;
  unsigned int* V1s  = (unsigned int*)(ws);           // 180 u   (720 B)
  float*        V1b  = (float*)(ws + 768);            // 45 f    (180 B)
  unsigned int* V2s  = (unsigned int*)(ws + 1024);    // 900 u   (3,600 B)
  float*        V2b  = (float*)(ws + 4672);           // 225 f   (900 B)
  unsigned int* V3s  = (unsigned int*)(ws + 5632);    // 360 u   (1,440 B)
  float*        V3b  = (float*)(ws + 7168);           // 90 f    (360 B)
  float*        W2p  = (float*)(ws + 7680);           // 5,120 f (20,480 B)
  unsigned int* W1p4 = (unsigned int*)(ws + 28672);   // 43,008 u (172,032 B)

  k_prep<<<168, 256, 0, stream>>>(bw1, sw1, bw2, sw2, bw3, sw3, w1, w2,
                                  V1s, V1b, V2s, V2b, V3s, V3b, W1p4, W2p);
  k_fused<<<2048, 64, 0, stream>>>(x, V1s, V1b, V2s, V2b, V3s, V3b,
                                   W1p4, W2p, b1, b2, out);
}

// Round 13
// 136.527 us; speedup vs baseline: 1.1710x; 1.0020x over previous
//
#include <hip/hip_runtime.h>

// ---------------------------------------------------------------------------
// Fully-fused KAN-conv MLP: ONE WAVE = ONE IMAGE, zero __syncthreads.
// Cardinal cubic B-spline: basis_j(x) = B3(u - j), u = 2.5x+5.5 (4 taps).
// Per-wave LDS slice: bas[pix] = uint4 (8 f16 taps) + slu16[pix] = silu f16.
// R13 changes vs R12:
//  - conv2/conv3 interchanged to positions-inner: weights + both position-
//    chunks' records load once per cky -> HALF the lgkmcnt(0) drains (SMEM
//    weights force full drains; fewer drains = fewer exposed latencies).
//  - fc1 manual double-buffer: W1p4 global loads ride vmcnt (in-order,
//    separate from LDS lgkmcnt) -> true prefetch of group g+1 during g.
//  - slu stored as f16 -> 15.2 KB/block -> 10 blocks/CU (was 9).
// h3 / hpk / fc1out all live in dead regions of bas after conv3.
// ---------------------------------------------------------------------------

typedef _Float16 h2 __attribute__((ext_vector_type(2)));

__device__ __forceinline__ h2 u2h(unsigned int u) {
  union { unsigned int x; h2 h; } v; v.x = u; return v.h;
}
__device__ __forceinline__ unsigned short f2h_bits(float x) {
  union { _Float16 h; unsigned short u; } v; v.h = (_Float16)x; return v.u;
}
__device__ __forceinline__ float h2f(unsigned short u) {
  union { unsigned short u; _Float16 h; } v; v.u = u; return (float)v.h;
}
__device__ __forceinline__ unsigned int pack2h(float a, float b) {
  return (unsigned int)f2h_bits(a) | ((unsigned int)f2h_bits(b) << 16);
}
__device__ __forceinline__ float fdot2(h2 a, h2 b, float c) {
  return __builtin_amdgcn_fdot2(a, b, c, false);
}

// Basis window (8 f16 packed in uint4) + silu, all in registers.
__device__ __forceinline__ void featurize_regs(float v, uint4& bs, float& silu) {
  silu = v / (1.0f + __expf(-v));
  bs.x = 0u; bs.y = 0u; bs.z = 0u; bs.w = 0u;
  float u = fmaf(v, 2.5f, 5.5f);
  if (u >= 0.0f && u < 11.0f) {
    float tf = floorf(u);
    float f = u - tf, f2 = f * f, f3 = f2 * f, om = 1.0f - f;
    const float c6 = 1.0f / 6.0f;
    float w0 = om * om * om * c6;
    float w1 = (3.0f * f3 - 6.0f * f2 + 4.0f) * c6;
    float w2 = (-3.0f * f3 + 3.0f * f2 + 3.0f * f + 1.0f) * c6;
    float w3 = f3 * c6;
    unsigned long long w01 =
        (unsigned long long)f2h_bits(w0) |
        ((unsigned long long)f2h_bits(w1) << 16) |
        ((unsigned long long)f2h_bits(w2) << 32) |
        ((unsigned long long)f2h_bits(w3) << 48);
    int t = (int)tf;                 // 0..10; window starts at slot t-3
    int s = 16 * t - 48;             // bit shift into 128-bit field
    unsigned long long lo, hi;
    if (s >= 0) {
      lo = (s < 64) ? (w01 << s) : 0ull;
      hi = (s == 0) ? 0ull : ((s < 64) ? (w01 >> (64 - s)) : (w01 << (s - 64)));
    } else {
      lo = w01 >> (-s);
      hi = 0ull;
    }
    bs.x = (unsigned int)lo; bs.y = (unsigned int)(lo >> 32);
    bs.z = (unsigned int)hi; bs.w = (unsigned int)(hi >> 32);
  }
}

// ---------------- prep: conv weights + W1p4 + padded W2 ---------------------
__global__ __launch_bounds__(256) void k_prep(
    const float* __restrict__ bw1, const float* __restrict__ sw1,
    const float* __restrict__ bw2, const float* __restrict__ sw2,
    const float* __restrict__ bw3, const float* __restrict__ sw3,
    const float* __restrict__ w1, const float* __restrict__ w2,
    unsigned int* __restrict__ V1s, float* __restrict__ V1b,
    unsigned int* __restrict__ V2s, float* __restrict__ V2b,
    unsigned int* __restrict__ V3s, float* __restrict__ V3b,
    unsigned int* __restrict__ W1p4, float* __restrict__ W2p) {
  int t = blockIdx.x * 256 + threadIdx.x;
  if (t < 180) {  // L1: 9 taps x 5 outs x 4 pairs
    int p = t & 3, o = (t >> 2) % 5, in = t / 20;
    V1s[t] = pack2h(sw1[(o * 9 + in) * 8 + 2 * p], sw1[(o * 9 + in) * 8 + 2 * p + 1]);
  }
  if (t < 45)  { int o = t % 5, in = t / 5; V1b[t] = bw1[o * 9 + in]; }
  if (t < 900) { // L2: 45 taps x 5 outs x 4 pairs
    int p = t & 3, o = (t >> 2) % 5, in = t / 20;
    V2s[t] = pack2h(sw2[(o * 45 + in) * 8 + 2 * p], sw2[(o * 45 + in) * 8 + 2 * p + 1]);
  }
  if (t < 225) { int o = t % 5, in = t / 5; V2b[t] = bw2[o * 45 + in]; }
  if (t < 360) { // L3: 45 taps x 2 outs x 4 pairs
    int p = t & 3, o = (t >> 2) & 1, in = t / 8;
    V3s[t] = pack2h(sw3[(o * 45 + in) * 8 + 2 * p], sw3[(o * 45 + in) * 8 + 2 * p + 1]);
  }
  if (t < 90)  { int o = t % 2, in = t / 2; V3b[t] = bw3[o * 45 + in]; }
  if (t < 43008) {  // W1p4[((g*512)+o)*4+j]: j-th k-pair of group g, out o
    int j = t & 3, o = (t >> 2) & 511, g = t >> 11;
    int kp = g * 4 + j;
    W1p4[t] = (o < 500 && kp < 81)
                  ? pack2h(w1[o * 162 + 2 * kp], w1[o * 162 + 2 * kp + 1])
                  : 0u;
  }
  if (t < 5120) {   // W2p[10][512] zero-padded
    int o = t >> 9, k = t & 511;
    W2p[t] = (k < 500) ? w2[o * 500 + k] : 0.0f;
  }
}

// ---------------- the fused per-image kernel (one wave per block) -----------
__global__ __launch_bounds__(64, 2) void k_fused(
    const float* __restrict__ x,
    const unsigned int* __restrict__ V1s, const float* __restrict__ V1b,
    const unsigned int* __restrict__ V2s, const float* __restrict__ V2b,
    const unsigned int* __restrict__ V3s, const float* __restrict__ V3b,
    const unsigned int* __restrict__ W1p4, const float* __restrict__ W2p,
    const float* __restrict__ b1, const float* __restrict__ b2,
    float* __restrict__ out) {
  __shared__ uint4 bas[845];               // 13,520 B
  __shared__ unsigned short slu16[848];    //  1,696 B
  float*        basF = (float*)bas;        // dword view of bas
  float*        h3f  = basF + 2048;        // h3 (162 f), dead-by-order region
  unsigned int* hpk  = (unsigned int*)basF + 2560;  // 84 uints
  const int b = blockIdx.x;
  const int lane = threadIdx.x;            // 0..63, one wave

  // P1: featurize input image (784 px)
  #pragma unroll 1
  for (int l = lane; l < 784; l += 64) {
    uint4 bs; float sl;
    featurize_regs(x[b * 784 + l], bs, sl);
    bas[l] = bs; slu16[l] = f2h_bits(sl);
  }

  // P2: conv1 (1->5) + 2x2 maxpool; 169 outputs in 3 chunks, staged in regs
  float h1v[3][5];
  #pragma unroll 1
  for (int it = 0; it < 3; ++it) {
    int p = it * 64 + lane;
    if (p < 169) {
      int py = p / 13, px = p % 13;
      int r0 = py * 2, c0 = px * 2;
      float wacc[4][5];
      #pragma unroll
      for (int wi = 0; wi < 4; ++wi)
        #pragma unroll
        for (int o = 0; o < 5; ++o) wacc[wi][o] = 0.0f;
      #pragma unroll
      for (int r = 0; r < 4; ++r) {
        uint4 q[4]; float sl[4];
        #pragma unroll
        for (int c = 0; c < 4; ++c) {
          q[c]  = bas[(r0 + r) * 28 + c0 + c];
          sl[c] = h2f(slu16[(r0 + r) * 28 + c0 + c]);
        }
        #pragma unroll
        for (int c = 0; c < 4; ++c) {
          h2 a0 = u2h(q[c].x), a1 = u2h(q[c].y), a2 = u2h(q[c].z), a3 = u2h(q[c].w);
          #pragma unroll
          for (int dy = 0; dy < 2; ++dy) {
            #pragma unroll
            for (int dx = 0; dx < 2; ++dx) {
              int ky = r - dy, kx = c - dx;
              if (ky >= 0 && ky < 3 && kx >= 0 && kx < 3) {
                const unsigned int* wp = V1s + (ky * 3 + kx) * 20;
                const float* bp = V1b + (ky * 3 + kx) * 5;
                #pragma unroll
                for (int o = 0; o < 5; ++o) {
                  float acc = wacc[dy * 2 + dx][o];
                  acc = fdot2(a0, u2h(wp[o * 4 + 0]), acc);
                  acc = fdot2(a1, u2h(wp[o * 4 + 1]), acc);
                  acc = fdot2(a2, u2h(wp[o * 4 + 2]), acc);
                  acc = fdot2(a3, u2h(wp[o * 4 + 3]), acc);
                  wacc[dy * 2 + dx][o] = fmaf(sl[c], bp[o], acc);
                }
              }
            }
          }
        }
      }
      #pragma unroll
      for (int o = 0; o < 5; ++o)
        h1v[it][o] = fmaxf(fmaxf(wacc[0][o], wacc[1][o]),
                           fmaxf(wacc[2][o], wacc[3][o]));
    }
  }
  // write featurized h1 (after ALL conv1 reads; in-order DS keeps this safe)
  #pragma unroll 1
  for (int it = 0; it < 3; ++it) {
    int p = it * 64 + lane;
    if (p < 169) {
      #pragma unroll
      for (int o = 0; o < 5; ++o) {
        uint4 bs; float sl;
        featurize_regs(h1v[it][o], bs, sl);
        bas[o * 169 + p] = bs; slu16[o * 169 + p] = f2h_bits(sl);
      }
    }
  }

  // P4: conv2 (5->5), positions-INNER: weights+records load once per cky
  float acc2[2][5];
  {
    #pragma unroll
    for (int ct = 0; ct < 2; ++ct)
      #pragma unroll
      for (int o = 0; o < 5; ++o) acc2[ct][o] = 0.0f;
    int pos0 = lane;                      // always < 121
    int y0 = pos0 / 11, x0 = pos0 % 11;
    int pos1 = 64 + lane;
    int p1c = (pos1 < 121) ? pos1 : 120;  // clamp (writeback guarded)
    int y1 = p1c / 11, x1 = p1c % 11;
    #pragma unroll 1
    for (int cky = 0; cky < 15; ++cky) {
      int c = cky / 3, ky = cky - c * 3;
      int ba0 = c * 169 + (y0 + ky) * 13 + x0;
      int ba1 = c * 169 + (y1 + ky) * 13 + x1;
      uint4 q00 = bas[ba0], q01 = bas[ba0 + 1], q02 = bas[ba0 + 2];
      uint4 q10 = bas[ba1], q11 = bas[ba1 + 1], q12 = bas[ba1 + 2];
      float s00 = h2f(slu16[ba0]), s01 = h2f(slu16[ba0 + 1]), s02 = h2f(slu16[ba0 + 2]);
      float s10 = h2f(slu16[ba1]), s11 = h2f(slu16[ba1 + 1]), s12 = h2f(slu16[ba1 + 2]);
      uint4 wq[15]; float wb[15];
      const uint4* wp4 = (const uint4*)(V2s + cky * 60);
      const float* bp  = V2b + cky * 15;
      #pragma unroll
      for (int i = 0; i < 15; ++i) { wq[i] = wp4[i]; wb[i] = bp[i]; }
      #pragma unroll
      for (int ct = 0; ct < 2; ++ct) {
        #pragma unroll
        for (int kx = 0; kx < 3; ++kx) {
          uint4 q = ct ? ((kx == 0) ? q10 : ((kx == 1) ? q11 : q12))
                       : ((kx == 0) ? q00 : ((kx == 1) ? q01 : q02));
          float sl = ct ? ((kx == 0) ? s10 : ((kx == 1) ? s11 : s12))
                        : ((kx == 0) ? s00 : ((kx == 1) ? s01 : s02));
          h2 a0 = u2h(q.x), a1 = u2h(q.y), a2 = u2h(q.z), a3 = u2h(q.w);
          #pragma unroll
          for (int o = 0; o < 5; ++o) {
            uint4 w = wq[kx * 5 + o];
            float a = acc2[ct][o];
            a = fdot2(a0, u2h(w.x), a);
            a = fdot2(a1, u2h(w.y), a);
            a = fdot2(a2, u2h(w.z), a);
            a = fdot2(a3, u2h(w.w), a);
            acc2[ct][o] = fmaf(sl, wb[kx * 5 + o], a);
          }
        }
      }
    }
  }
  // write featurized h2 (after all conv2 reads)
  #pragma unroll 1
  for (int ct = 0; ct < 2; ++ct) {
    int pos = ct * 64 + lane;
    if (pos < 121) {
      #pragma unroll
      for (int o = 0; o < 5; ++o) {
        uint4 bs; float sl;
        featurize_regs(acc2[ct][o], bs, sl);
        bas[o * 121 + pos] = bs; slu16[o * 121 + pos] = f2h_bits(sl);
      }
    }
  }

  // P6: conv3 (5->2), positions-INNER
  float acc3[2][2];
  {
    acc3[0][0] = acc3[0][1] = acc3[1][0] = acc3[1][1] = 0.0f;
    int pos0 = lane;                      // < 81 (lane<=63)
    int y0 = pos0 / 9, x0 = pos0 % 9;
    int pos1 = 64 + lane;
    int p1c = (pos1 < 81) ? pos1 : 80;
    int y1 = p1c / 9, x1 = p1c % 9;
    #pragma unroll 1
    for (int cky = 0; cky < 15; ++cky) {
      int c = cky / 3, ky = cky - c * 3;
      int ba0 = c * 121 + (y0 + ky) * 11 + x0;
      int ba1 = c * 121 + (y1 + ky) * 11 + x1;
      uint4 q00 = bas[ba0], q01 = bas[ba0 + 1], q02 = bas[ba0 + 2];
      uint4 q10 = bas[ba1], q11 = bas[ba1 + 1], q12 = bas[ba1 + 2];
      float s00 = h2f(slu16[ba0]), s01 = h2f(slu16[ba0 + 1]), s02 = h2f(slu16[ba0 + 2]);
      float s10 = h2f(slu16[ba1]), s11 = h2f(slu16[ba1 + 1]), s12 = h2f(slu16[ba1 + 2]);
      uint4 wq[6]; float wb[6];
      const uint4* wp4 = (const uint4*)(V3s + cky * 24);
      const float* bp  = V3b + cky * 6;
      #pragma unroll
      for (int i = 0; i < 6; ++i) { wq[i] = wp4[i]; wb[i] = bp[i]; }
      #pragma unroll
      for (int ct = 0; ct < 2; ++ct) {
        #pragma unroll
        for (int kx = 0; kx < 3; ++kx) {
          uint4 q = ct ? ((kx == 0) ? q10 : ((kx == 1) ? q11 : q12))
                       : ((kx == 0) ? q00 : ((kx == 1) ? q01 : q02));
          float sl = ct ? ((kx == 0) ? s10 : ((kx == 1) ? s11 : s12))
                        : ((kx == 0) ? s00 : ((kx == 1) ? s01 : s02));
          h2 a0 = u2h(q.x), a1 = u2h(q.y), a2 = u2h(q.z), a3 = u2h(q.w);
          #pragma unroll
          for (int o = 0; o < 2; ++o) {
            uint4 w = wq[kx * 2 + o];
            float a = acc3[ct][o];
            a = fdot2(a0, u2h(w.x), a);
            a = fdot2(a1, u2h(w.y), a);
            a = fdot2(a2, u2h(w.z), a);
            a = fdot2(a3, u2h(w.w), a);
            acc3[ct][o] = fmaf(sl, wb[kx * 2 + o], a);
          }
        }
      }
    }
  }
  // write h3 (f32) into h3f[0..161] (bas region, post-read) then pack
  #pragma unroll 1
  for (int ct = 0; ct < 2; ++ct) {
    int pos = ct * 64 + lane;
    if (pos < 81) { h3f[pos] = acc3[ct][0]; h3f[81 + pos] = acc3[ct][1]; }
  }
  hpk[lane] = pack2h(h3f[2 * lane], h3f[2 * lane + 1]);
  {
    int i1 = 64 + lane;
    if (i1 < 84)
      hpk[i1] = (i1 < 81) ? pack2h(h3f[2 * i1], h3f[2 * i1 + 1]) : 0u;
  }

  // P7: fc1 (162->500) + bias + ReLU; 8 outs/lane; double-buffered global
  // loads (vmcnt is in-order & separate from LDS lgkmcnt -> real prefetch).
  float fa[8];
  #pragma unroll
  for (int i = 0; i < 8; ++i) fa[i] = 0.0f;
  {
    const uint4* hp4 = (const uint4*)hpk;
    const uint4* wbase = (const uint4*)W1p4 + lane;
    uint4 wA[8], wB[8];
    #pragma unroll
    for (int i = 0; i < 8; ++i) wA[i] = wbase[i * 64];   // group 0
    #pragma unroll 1
    for (int g = 0; g < 21; g += 2) {
      if (g + 1 < 21) {
        const uint4* p = wbase + (g + 1) * 512;
        #pragma unroll
        for (int i = 0; i < 8; ++i) wB[i] = p[i * 64];
      }
      {
        uint4 hk = hp4[g];
        #pragma unroll
        for (int i = 0; i < 8; ++i) {
          float a = fa[i];
          a = fdot2(u2h(hk.x), u2h(wA[i].x), a);
          a = fdot2(u2h(hk.y), u2h(wA[i].y), a);
          a = fdot2(u2h(hk.z), u2h(wA[i].z), a);
          a = fdot2(u2h(hk.w), u2h(wA[i].w), a);
          fa[i] = a;
        }
      }
      if (g + 2 < 21) {
        const uint4* p = wbase + (g + 2) * 512;
        #pragma unroll
        for (int i = 0; i < 8; ++i) wA[i] = p[i * 64];
      }
      if (g + 1 < 21) {
        uint4 hk = hp4[g + 1];
        #pragma unroll
        for (int i = 0; i < 8; ++i) {
          float a = fa[i];
          a = fdot2(u2h(hk.x), u2h(wB[i].x), a);
          a = fdot2(u2h(hk.y), u2h(wB[i].y), a);
          a = fdot2(u2h(hk.z), u2h(wB[i].z), a);
          a = fdot2(u2h(hk.w), u2h(wB[i].w), a);
          fa[i] = a;
        }
      }
    }
  }
  #pragma unroll
  for (int i = 0; i < 8; ++i) {
    int o = lane + 64 * i;
    float bb = (o < 500) ? b1[o] : 0.0f;
    float v = fa[i] + bb;
    basF[o] = (v > 0.0f && o < 500) ? v : 0.0f;  // fc1out[512] in bas[0..127]
  }

  // P8: fc2 (500->10): lane covers k = 8*lane..8*lane+7, shfl reduction
  float hv0, hv1, hv2, hv3, hv4, hv5, hv6, hv7;
  {
    const float4* hf = (const float4*)&basF[lane * 8];
    float4 ha = hf[0], hb = hf[1];
    hv0 = ha.x; hv1 = ha.y; hv2 = ha.z; hv3 = ha.w;
    hv4 = hb.x; hv5 = hb.y; hv6 = hb.z; hv7 = hb.w;
  }
  float acc10[10];
  #pragma unroll
  for (int o = 0; o < 10; ++o) {
    const float4* wp = (const float4*)&W2p[o * 512 + lane * 8];
    float4 w0 = wp[0], w1v = wp[1];
    float s = hv0 * w0.x + hv1 * w0.y + hv2 * w0.z + hv3 * w0.w;
    s += hv4 * w1v.x + hv5 * w1v.y + hv6 * w1v.z + hv7 * w1v.w;
    acc10[o] = s;
  }
  #pragma unroll
  for (int off = 32; off > 0; off >>= 1) {
    #pragma unroll
    for (int o = 0; o < 10; ++o) acc10[o] += __shfl_down(acc10[o], off);
  }
  if (lane == 0) {
    #pragma unroll
    for (int o = 0; o < 10; ++o) out[b * 10 + o] = acc10[o] + b2[o];
  }
}

// ---------------------------------------------------------------------------
extern "C" void kernel_launch(void* const* d_in, const int* in_sizes, int n_in,
                              void* d_out, int out_size, void* d_ws, size_t ws_size,
                              hipStream_t stream) {
  (void)in_sizes; (void)n_in; (void)out_size; (void)ws_size;
  const float* x   = (const float*)d_in[0];
  const float* bw1 = (const float*)d_in[1];
  const float* sw1 = (const float*)d_in[2];
  const float* bw2 = (const float*)d_in[3];
  const float* sw2 = (const float*)d_in[4];
  const float* bw3 = (const float*)d_in[5];
  const float* sw3 = (const float*)d_in[6];
  const float* w1  = (const float*)d_in[7];
  const float* b1  = (const float*)d_in[8];
  const float* w2  = (const float*)d_in[9];
  const float* b2  = (const float*)d_in[10];
  float* out = (float*)d_out;

  char* ws = (char*)d_ws;
  unsigned int* V1s  = (unsigned int*)(ws);           // 180 u   (720 B)
  float*        V1b  = (float*)(ws + 768);            // 45 f    (180 B)
  unsigned int* V2s  = (unsigned int*)(ws + 1024);    // 900 u   (3,600 B)
  float*        V2b  = (float*)(ws + 4672);           // 225 f   (900 B)
  unsigned int* V3s  = (unsigned int*)(ws + 5632);    // 360 u   (1,440 B)
  float*        V3b  = (float*)(ws + 7168);           // 90 f    (360 B)
  float*        W2p  = (float*)(ws + 7680);           // 5,120 f (20,480 B)
  unsigned int* W1p4 = (unsigned int*)(ws + 28672);   // 43,008 u (172,032 B)

  k_prep<<<168, 256, 0, stream>>>(bw1, sw1, bw2, sw2, bw3, sw3, w1, w2,
                                  V1s, V1b, V2s, V2b, V3s, V3b, W1p4, W2p);
  k_fused<<<2048, 64, 0, stream>>>(x, V1s, V1b, V2s, V2b, V3s, V3b,
                                   W1p4, W2p, b1, b2, out);
}